// Round 1
// baseline (2972.410 us; speedup 1.0000x reference)
//
#include <hip/hip_runtime.h>

// Problem constants (from reference): N=50000, F_IN=512, F_OUT=128, E=1.6M
#define F_IN   512
#define F_OUT  128
#define BM     128
#define BK     32

// ---------------------------------------------------------------------------
// GEMM: X[M, 128] = (A[M,512] * Mask[M,512]) @ B[512,128]
// 256 threads, 128x128 tile, 8x8 per-thread micro-tile (split 4+4 strided by 64)
// A staged transposed in LDS (As[k][m]) so fragment reads are ds_read_b128.
// ---------------------------------------------------------------------------
__global__ __launch_bounds__(256, 2) void gemm_dropout_kernel(
    const float* __restrict__ A, const float* __restrict__ Mask,
    const float* __restrict__ B, float* __restrict__ X, int M) {
  __shared__ float As[BK][BM + 4];   // [k][m], pad 4 floats: keeps 16B align, breaks bank aliasing
  __shared__ float Bs[BK][F_OUT + 4];

  const int tid = threadIdx.x;
  const int tx = tid & 15;          // column group
  const int ty = (tid >> 4) & 15;   // row group
  const int bm = blockIdx.x * BM;

  float acc[8][8];
#pragma unroll
  for (int i = 0; i < 8; ++i)
#pragma unroll
    for (int j = 0; j < 8; ++j) acc[i][j] = 0.f;

  for (int k0 = 0; k0 < F_IN; k0 += BK) {
    // Stage A-tile (128 rows x 32 k) fused with dropout mask; store transposed.
#pragma unroll
    for (int i = 0; i < 4; ++i) {
      int idx = tid + i * 256;            // 0..1023 float4 slots
      int r = idx >> 3;                   // row in tile 0..127
      int c = (idx & 7) << 2;             // k offset 0,4,...,28
      int row = bm + r; if (row >= M) row = M - 1;   // clamp (stores are guarded)
      const float4 a = *(const float4*)(A    + (size_t)row * F_IN + k0 + c);
      const float4 m = *(const float4*)(Mask + (size_t)row * F_IN + k0 + c);
      As[c + 0][r] = a.x * m.x;
      As[c + 1][r] = a.y * m.y;
      As[c + 2][r] = a.z * m.z;
      As[c + 3][r] = a.w * m.w;
    }
    // Stage B-tile (32 k x 128 n)
#pragma unroll
    for (int i = 0; i < 4; ++i) {
      int idx = tid + i * 256;            // 0..1023 float4 slots
      int r = idx >> 5;                   // k 0..31
      int c = (idx & 31) << 2;            // n 0..124
      *(float4*)(&Bs[r][c]) = *(const float4*)(B + (size_t)(k0 + r) * F_OUT + c);
    }
    __syncthreads();

#pragma unroll
    for (int kk = 0; kk < BK; ++kk) {
      float a[8], bb[8];
      *(float4*)(a)      = *(const float4*)(&As[kk][ty * 4]);
      *(float4*)(a + 4)  = *(const float4*)(&As[kk][ty * 4 + 64]);
      *(float4*)(bb)     = *(const float4*)(&Bs[kk][tx * 4]);
      *(float4*)(bb + 4) = *(const float4*)(&Bs[kk][tx * 4 + 64]);
#pragma unroll
      for (int i = 0; i < 8; ++i)
#pragma unroll
        for (int j = 0; j < 8; ++j) acc[i][j] += a[i] * bb[j];
    }
    __syncthreads();
  }

  // Store 8x8 micro-tile: rows {ty*4+i, 64+ty*4+i}, cols {tx*4+j, 64+tx*4+j}
#pragma unroll
  for (int i = 0; i < 8; ++i) {
    int r_local = (i < 4) ? (ty * 4 + i) : (64 + ty * 4 + (i - 4));
    int row = bm + r_local;
    if (row < M) {
      float4 lo = make_float4(acc[i][0], acc[i][1], acc[i][2], acc[i][3]);
      float4 hi = make_float4(acc[i][4], acc[i][5], acc[i][6], acc[i][7]);
      *(float4*)(X + (size_t)row * F_OUT + tx * 4)      = lo;
      *(float4*)(X + (size_t)row * F_OUT + 64 + tx * 4) = hi;
    }
  }
}

// ---------------------------------------------------------------------------
// SpMM scatter: out[rows[e]] += vals[e] * X[cols[e]]   (atomicAdd per float)
// 32 lanes per edge, float4 per lane (128 floats per edge).
// ---------------------------------------------------------------------------
__global__ __launch_bounds__(256) void spmm_scatter_kernel(
    const int* __restrict__ rows, const int* __restrict__ cols,
    const float* __restrict__ vals, const float* __restrict__ X,
    float* __restrict__ out, int E) {
  const int t = blockIdx.x * blockDim.x + threadIdx.x;
  const int nthreads = gridDim.x * blockDim.x;
  const int sub = t & 31;                 // feature sub-slot (4 floats each)
  const int estep = nthreads >> 5;

  for (int e = t >> 5; e < E; e += estep) {
    const int   r = rows[e];
    const int   c = cols[e];
    const float v = vals[e];
    const float4 x4 = *(const float4*)(X + ((size_t)c << 7) + (sub << 2));
    float* o = out + ((size_t)r << 7) + (sub << 2);
    atomicAdd(o + 0, v * x4.x);
    atomicAdd(o + 1, v * x4.y);
    atomicAdd(o + 2, v * x4.z);
    atomicAdd(o + 3, v * x4.w);
  }
}

// ---------------------------------------------------------------------------
// Epilogue: out = relu(out + b), float4 grid-stride
// ---------------------------------------------------------------------------
__global__ __launch_bounds__(256) void bias_relu_kernel(
    float* __restrict__ out, const float* __restrict__ b, int total4) {
  int i = blockIdx.x * blockDim.x + threadIdx.x;
  const int stride = gridDim.x * blockDim.x;
  for (; i < total4; i += stride) {
    float4 v = ((const float4*)out)[i];
    const float4 bb = ((const float4*)b)[i & 31];   // 128 floats = 32 float4 per row
    v.x = fmaxf(v.x + bb.x, 0.f);
    v.y = fmaxf(v.y + bb.y, 0.f);
    v.z = fmaxf(v.z + bb.z, 0.f);
    v.w = fmaxf(v.w + bb.w, 0.f);
    ((float4*)out)[i] = v;
  }
}

extern "C" void kernel_launch(void* const* d_in, const int* in_sizes, int n_in,
                              void* d_out, int out_size, void* d_ws, size_t ws_size,
                              hipStream_t stream) {
  const float* features  = (const float*)d_in[0];
  const float* drop_mask = (const float*)d_in[1];
  const float* W         = (const float*)d_in[2];
  const float* b         = (const float*)d_in[3];
  const int*   adj_rows  = (const int*)d_in[4];
  const int*   adj_cols  = (const int*)d_in[5];
  const float* adj_vals  = (const float*)d_in[6];

  float* out = (float*)d_out;
  float* X   = (float*)d_ws;                 // [M, 128] dense projection scratch

  const int M = in_sizes[0] / F_IN;          // 50000
  const int E = in_sizes[4];                 // 1.6M

  // out starts poisoned (0xAA) — zero it for the atomic accumulation.
  hipMemsetAsync(d_out, 0, (size_t)out_size * sizeof(float), stream);

  gemm_dropout_kernel<<<(M + BM - 1) / BM, 256, 0, stream>>>(features, drop_mask, W, X, M);
  spmm_scatter_kernel<<<2048, 256, 0, stream>>>(adj_rows, adj_cols, adj_vals, X, out, E);
  bias_relu_kernel<<<2048, 256, 0, stream>>>(out, b, (M * F_OUT) / 4);
}

// Round 2
// 613.635 us; speedup vs baseline: 4.8439x; 4.8439x over previous
//
#include <hip/hip_runtime.h>

// Problem constants (from reference): N=50000, F_IN=512, F_OUT=128, E=1.6M
#define F_IN   512
#define F_OUT  128
#define BM     128
#define BK     32

// ---------------------------------------------------------------------------
// GEMM: X[M, 128] = (A[M,512] * Mask[M,512]) @ B[512,128]
// 256 threads, 128x128 tile, 8x8 per-thread micro-tile (split 4+4 strided by 64)
// ---------------------------------------------------------------------------
__global__ __launch_bounds__(256, 2) void gemm_dropout_kernel(
    const float* __restrict__ A, const float* __restrict__ Mask,
    const float* __restrict__ B, float* __restrict__ X, int M) {
  __shared__ float As[BK][BM + 4];
  __shared__ float Bs[BK][F_OUT + 4];

  const int tid = threadIdx.x;
  const int tx = tid & 15;
  const int ty = (tid >> 4) & 15;
  const int bm = blockIdx.x * BM;

  float acc[8][8];
#pragma unroll
  for (int i = 0; i < 8; ++i)
#pragma unroll
    for (int j = 0; j < 8; ++j) acc[i][j] = 0.f;

  for (int k0 = 0; k0 < F_IN; k0 += BK) {
#pragma unroll
    for (int i = 0; i < 4; ++i) {
      int idx = tid + i * 256;
      int r = idx >> 3;
      int c = (idx & 7) << 2;
      int row = bm + r; if (row >= M) row = M - 1;
      const float4 a = *(const float4*)(A    + (size_t)row * F_IN + k0 + c);
      const float4 m = *(const float4*)(Mask + (size_t)row * F_IN + k0 + c);
      As[c + 0][r] = a.x * m.x;
      As[c + 1][r] = a.y * m.y;
      As[c + 2][r] = a.z * m.z;
      As[c + 3][r] = a.w * m.w;
    }
#pragma unroll
    for (int i = 0; i < 4; ++i) {
      int idx = tid + i * 256;
      int r = idx >> 5;
      int c = (idx & 31) << 2;
      *(float4*)(&Bs[r][c]) = *(const float4*)(B + (size_t)(k0 + r) * F_OUT + c);
    }
    __syncthreads();

#pragma unroll
    for (int kk = 0; kk < BK; ++kk) {
      float a[8], bb[8];
      *(float4*)(a)      = *(const float4*)(&As[kk][ty * 4]);
      *(float4*)(a + 4)  = *(const float4*)(&As[kk][ty * 4 + 64]);
      *(float4*)(bb)     = *(const float4*)(&Bs[kk][tx * 4]);
      *(float4*)(bb + 4) = *(const float4*)(&Bs[kk][tx * 4 + 64]);
#pragma unroll
      for (int i = 0; i < 8; ++i)
#pragma unroll
        for (int j = 0; j < 8; ++j) acc[i][j] += a[i] * bb[j];
    }
    __syncthreads();
  }

#pragma unroll
  for (int i = 0; i < 8; ++i) {
    int r_local = (i < 4) ? (ty * 4 + i) : (64 + ty * 4 + (i - 4));
    int row = bm + r_local;
    if (row < M) {
      float4 lo = make_float4(acc[i][0], acc[i][1], acc[i][2], acc[i][3]);
      float4 hi = make_float4(acc[i][4], acc[i][5], acc[i][6], acc[i][7]);
      *(float4*)(X + (size_t)row * F_OUT + tx * 4)      = lo;
      *(float4*)(X + (size_t)row * F_OUT + 64 + tx * 4) = hi;
    }
  }
}

// ---------------------------------------------------------------------------
// CSR build stage 1: histogram of row ids (int atomics, low contention)
// ---------------------------------------------------------------------------
__global__ __launch_bounds__(256) void hist_kernel(
    const int* __restrict__ rows, int* __restrict__ count, int E) {
  int i = blockIdx.x * blockDim.x + threadIdx.x;
  const int stride = gridDim.x * blockDim.x;
  for (; i < E; i += stride) atomicAdd(&count[rows[i]], 1);
}

// Stage 2a: per-chunk (256 counts) sums
__global__ __launch_bounds__(256) void chunk_reduce_kernel(
    const int* __restrict__ count, int* __restrict__ partial, int M) {
  __shared__ int s[256];
  const int t = threadIdx.x;
  const int i = blockIdx.x * 256 + t;
  s[t] = (i < M) ? count[i] : 0;
  __syncthreads();
#pragma unroll
  for (int off = 128; off > 0; off >>= 1) {
    if (t < off) s[t] += s[t + off];
    __syncthreads();
  }
  if (t == 0) partial[blockIdx.x] = s[0];
}

// Stage 2b: serial exclusive scan of chunk sums (nchunk ~196, single thread)
__global__ void scan_partials_kernel(int* __restrict__ partial, int nchunk,
                                     int* __restrict__ row_start, int M) {
  if (threadIdx.x == 0 && blockIdx.x == 0) {
    int run = 0;
    for (int i = 0; i < nchunk; ++i) {
      int v = partial[i];
      partial[i] = run;
      run += v;
    }
    row_start[M] = run;   // == E
  }
}

// Stage 2c: per-chunk exclusive scan + chunk base -> row_start, cursor
__global__ __launch_bounds__(256) void chunk_scan_kernel(
    const int* __restrict__ count, const int* __restrict__ partial,
    int* __restrict__ row_start, int* __restrict__ cursor, int M) {
  __shared__ int s[256];
  const int t = threadIdx.x;
  const int i = blockIdx.x * 256 + t;
  const int x = (i < M) ? count[i] : 0;
  s[t] = x;
  __syncthreads();
  // Hillis-Steele inclusive scan
#pragma unroll
  for (int off = 1; off < 256; off <<= 1) {
    int y = (t >= off) ? s[t - off] : 0;
    __syncthreads();
    s[t] += y;
    __syncthreads();
  }
  if (i < M) {
    const int excl = s[t] - x + partial[blockIdx.x];
    row_start[i] = excl;
    cursor[i]    = excl;
  }
}

// Stage 3: scatter edges into CSR order (copy col+val; perm not needed)
__global__ __launch_bounds__(256) void scatter_kernel(
    const int* __restrict__ rows, const int* __restrict__ cols,
    const float* __restrict__ vals, int* __restrict__ cursor,
    int* __restrict__ edge_col, float* __restrict__ edge_val, int E) {
  int e = blockIdx.x * blockDim.x + threadIdx.x;
  const int stride = gridDim.x * blockDim.x;
  for (; e < E; e += stride) {
    const int r = rows[e];
    const int pos = atomicAdd(&cursor[r], 1);
    edge_col[pos] = cols[e];
    edge_val[pos] = vals[e];
  }
}

// ---------------------------------------------------------------------------
// CSR SpMM + fused bias/ReLU. One 64-lane wave per row; lane owns float2.
// out[r] = relu( sum_e val[e] * X[col[e]] + b )   — single write per element.
// ---------------------------------------------------------------------------
__global__ __launch_bounds__(256) void spmm_csr_kernel(
    const int* __restrict__ row_start, const int* __restrict__ edge_col,
    const float* __restrict__ edge_val, const float* __restrict__ X,
    const float* __restrict__ bias, float* __restrict__ out, int M) {
  const int lane = threadIdx.x & 63;
  const int wid  = __builtin_amdgcn_readfirstlane(threadIdx.x >> 6);
  const int r    = blockIdx.x * 4 + wid;
  if (r >= M) return;

  const int s = row_start[r];
  const int end = row_start[r + 1];

  float ax = 0.f, ay = 0.f;
  int e = s;
  // unroll x4: issue 4 independent gathers for memory-level parallelism
  for (; e + 3 < end; e += 4) {
    const int   c0 = edge_col[e],     c1 = edge_col[e + 1];
    const int   c2 = edge_col[e + 2], c3 = edge_col[e + 3];
    const float v0 = edge_val[e],     v1 = edge_val[e + 1];
    const float v2 = edge_val[e + 2], v3 = edge_val[e + 3];
    const float2 x0 = ((const float2*)(X + ((size_t)c0 << 7)))[lane];
    const float2 x1 = ((const float2*)(X + ((size_t)c1 << 7)))[lane];
    const float2 x2 = ((const float2*)(X + ((size_t)c2 << 7)))[lane];
    const float2 x3 = ((const float2*)(X + ((size_t)c3 << 7)))[lane];
    ax += v0 * x0.x + v1 * x1.x + v2 * x2.x + v3 * x3.x;
    ay += v0 * x0.y + v1 * x1.y + v2 * x2.y + v3 * x3.y;
  }
  for (; e < end; ++e) {
    const int   c = edge_col[e];
    const float v = edge_val[e];
    const float2 x = ((const float2*)(X + ((size_t)c << 7)))[lane];
    ax += v * x.x;
    ay += v * x.y;
  }

  const float2 bb = ((const float2*)bias)[lane];
  float2 res;
  res.x = fmaxf(ax + bb.x, 0.f);
  res.y = fmaxf(ay + bb.y, 0.f);
  ((float2*)(out + ((size_t)r << 7)))[lane] = res;
}

extern "C" void kernel_launch(void* const* d_in, const int* in_sizes, int n_in,
                              void* d_out, int out_size, void* d_ws, size_t ws_size,
                              hipStream_t stream) {
  const float* features  = (const float*)d_in[0];
  const float* drop_mask = (const float*)d_in[1];
  const float* W         = (const float*)d_in[2];
  const float* b         = (const float*)d_in[3];
  const int*   adj_rows  = (const int*)d_in[4];
  const int*   adj_cols  = (const int*)d_in[5];
  const float* adj_vals  = (const float*)d_in[6];

  float* out = (float*)d_out;

  const int M = in_sizes[0] / F_IN;          // 50000
  const int E = in_sizes[4];                 // 1.6M
  const int nchunk = (M + 255) / 256;        // 196

  // Workspace layout (all 4-byte types; ~39 MB total)
  float* X        = (float*)d_ws;            // M*128
  int*   edge_col = (int*)(X + (size_t)M * F_OUT);   // E
  float* edge_val = (float*)(edge_col + E);  // E
  int*   count    = (int*)(edge_val + E);    // M
  int*   row_start= count + M;               // M+1
  int*   cursor   = row_start + M + 1;       // M
  int*   partial  = cursor + M;              // nchunk

  // zero the histogram (rest of ws is written before read)
  hipMemsetAsync(count, 0, (size_t)M * sizeof(int), stream);

  gemm_dropout_kernel<<<(M + BM - 1) / BM, 256, 0, stream>>>(features, drop_mask, W, X, M);

  hist_kernel<<<2048, 256, 0, stream>>>(adj_rows, count, E);
  chunk_reduce_kernel<<<nchunk, 256, 0, stream>>>(count, partial, M);
  scan_partials_kernel<<<1, 64, 0, stream>>>(partial, nchunk, row_start, M);
  chunk_scan_kernel<<<nchunk, 256, 0, stream>>>(count, partial, row_start, cursor, M);
  scatter_kernel<<<2048, 256, 0, stream>>>(adj_rows, adj_cols, adj_vals, cursor,
                                           edge_col, edge_val, E);
  spmm_csr_kernel<<<(M + 3) / 4, 256, 0, stream>>>(row_start, edge_col, edge_val,
                                                   X, b, out, M);
}

// Round 3
// 576.188 us; speedup vs baseline: 5.1588x; 1.0650x over previous
//
#include <hip/hip_runtime.h>

// Problem constants (from reference): N=50000, F_IN=512, F_OUT=128, E=1.6M
#define F_IN   512
#define F_OUT  128
#define BM     128
#define BK     32

// Bucketing for the two-phase CSR build
#define BROWS      32          // rows per bucket  (bucket = row >> 5)
#define BSHIFT     5
#define BCAP       4096        // max edges per bucket staged in LDS (avg ~1024)
#define CUR_STRIDE 16          // bucket cursors padded to 64B to avoid line-serialized atomics

// ---------------------------------------------------------------------------
// GEMM: X[M, 128] = (A[M,512] * Mask[M,512]) @ B[512,128]
// 256 threads, 128x128 tile, 8x8 per-thread micro-tile (split 4+4 strided by 64)
// ---------------------------------------------------------------------------
__global__ __launch_bounds__(256, 2) void gemm_dropout_kernel(
    const float* __restrict__ A, const float* __restrict__ Mask,
    const float* __restrict__ B, float* __restrict__ X, int M) {
  __shared__ float As[BK][BM + 4];
  __shared__ float Bs[BK][F_OUT + 4];

  const int tid = threadIdx.x;
  const int tx = tid & 15;
  const int ty = (tid >> 4) & 15;
  const int bm = blockIdx.x * BM;

  float acc[8][8];
#pragma unroll
  for (int i = 0; i < 8; ++i)
#pragma unroll
    for (int j = 0; j < 8; ++j) acc[i][j] = 0.f;

  for (int k0 = 0; k0 < F_IN; k0 += BK) {
#pragma unroll
    for (int i = 0; i < 4; ++i) {
      int idx = tid + i * 256;
      int r = idx >> 3;
      int c = (idx & 7) << 2;
      int row = bm + r; if (row >= M) row = M - 1;
      const float4 a = *(const float4*)(A    + (size_t)row * F_IN + k0 + c);
      const float4 m = *(const float4*)(Mask + (size_t)row * F_IN + k0 + c);
      As[c + 0][r] = a.x * m.x;
      As[c + 1][r] = a.y * m.y;
      As[c + 2][r] = a.z * m.z;
      As[c + 3][r] = a.w * m.w;
    }
#pragma unroll
    for (int i = 0; i < 4; ++i) {
      int idx = tid + i * 256;
      int r = idx >> 5;
      int c = (idx & 31) << 2;
      *(float4*)(&Bs[r][c]) = *(const float4*)(B + (size_t)(k0 + r) * F_OUT + c);
    }
    __syncthreads();

#pragma unroll
    for (int kk = 0; kk < BK; ++kk) {
      float a[8], bb[8];
      *(float4*)(a)      = *(const float4*)(&As[kk][ty * 4]);
      *(float4*)(a + 4)  = *(const float4*)(&As[kk][ty * 4 + 64]);
      *(float4*)(bb)     = *(const float4*)(&Bs[kk][tx * 4]);
      *(float4*)(bb + 4) = *(const float4*)(&Bs[kk][tx * 4 + 64]);
#pragma unroll
      for (int i = 0; i < 8; ++i)
#pragma unroll
        for (int j = 0; j < 8; ++j) acc[i][j] += a[i] * bb[j];
    }
    __syncthreads();
  }

#pragma unroll
  for (int i = 0; i < 8; ++i) {
    int r_local = (i < 4) ? (ty * 4 + i) : (64 + ty * 4 + (i - 4));
    int row = bm + r_local;
    if (row < M) {
      float4 lo = make_float4(acc[i][0], acc[i][1], acc[i][2], acc[i][3]);
      float4 hi = make_float4(acc[i][4], acc[i][5], acc[i][6], acc[i][7]);
      *(float4*)(X + (size_t)row * F_OUT + tx * 4)      = lo;
      *(float4*)(X + (size_t)row * F_OUT + 64 + tx * 4) = hi;
    }
  }
}

// ---------------------------------------------------------------------------
// CSR build stage 1: histogram of row ids (int atomics, ~32 per counter)
// ---------------------------------------------------------------------------
__global__ __launch_bounds__(256) void hist_kernel(
    const int* __restrict__ rows, int* __restrict__ count, int E) {
  int i = blockIdx.x * blockDim.x + threadIdx.x;
  const int stride = gridDim.x * blockDim.x;
  for (; i < E; i += stride) atomicAdd(&count[rows[i]], 1);
}

// Stage 2a: per-chunk (256 counts) sums
__global__ __launch_bounds__(256) void chunk_reduce_kernel(
    const int* __restrict__ count, int* __restrict__ partial, int M) {
  __shared__ int s[256];
  const int t = threadIdx.x;
  const int i = blockIdx.x * 256 + t;
  s[t] = (i < M) ? count[i] : 0;
  __syncthreads();
#pragma unroll
  for (int off = 128; off > 0; off >>= 1) {
    if (t < off) s[t] += s[t + off];
    __syncthreads();
  }
  if (t == 0) partial[blockIdx.x] = s[0];
}

// Stage 2b: exclusive scan of chunk sums — one block, Hillis-Steele in LDS.
// (replaces the serial single-thread scan: ~196 dependent L2 round trips)
__global__ __launch_bounds__(256) void scan_partials_kernel(
    int* __restrict__ partial, int nchunk, int* __restrict__ row_start, int M) {
  if (nchunk <= 256) {
    __shared__ int s[256];
    const int t = threadIdx.x;
    const int v = (t < nchunk) ? partial[t] : 0;
    s[t] = v;
    __syncthreads();
#pragma unroll
    for (int off = 1; off < 256; off <<= 1) {
      int y = (t >= off) ? s[t - off] : 0;
      __syncthreads();
      s[t] += y;
      __syncthreads();
    }
    if (t < nchunk) partial[t] = s[t] - v;     // exclusive
    if (t == 255) row_start[M] = s[255];       // total == E
  } else if (threadIdx.x == 0) {               // generic fallback
    int run = 0;
    for (int i = 0; i < nchunk; ++i) { int v = partial[i]; partial[i] = run; run += v; }
    row_start[M] = run;
  }
}

// Stage 2c: per-chunk exclusive scan + chunk base -> row_start; also seed the
// padded bucket cursors (bucket_start[b] == row_start[b*BROWS] by construction).
__global__ __launch_bounds__(256) void chunk_scan_kernel(
    const int* __restrict__ count, const int* __restrict__ partial,
    int* __restrict__ row_start, int* __restrict__ bcursor, int M) {
  __shared__ int s[256];
  const int t = threadIdx.x;
  const int i = blockIdx.x * 256 + t;
  const int x = (i < M) ? count[i] : 0;
  s[t] = x;
  __syncthreads();
#pragma unroll
  for (int off = 1; off < 256; off <<= 1) {
    int y = (t >= off) ? s[t - off] : 0;
    __syncthreads();
    s[t] += y;
    __syncthreads();
  }
  if (i < M) {
    const int excl = s[t] - x + partial[blockIdx.x];
    row_start[i] = excl;
    if ((i & (BROWS - 1)) == 0) bcursor[(i >> BSHIFT) * CUR_STRIDE] = excl;
  }
}

// ---------------------------------------------------------------------------
// Stage 3: bucket scatter. One packed 8B record per edge into bucket-major
// order. Write working set = ~1563 advancing cursor regions -> L2-resident.
// record = ( (row<<16)|col , bits(val) )   [row, col < 65536]
// ---------------------------------------------------------------------------
__global__ __launch_bounds__(256) void bucket_scatter_kernel(
    const int* __restrict__ rows, const int* __restrict__ cols,
    const float* __restrict__ vals, int* __restrict__ bcursor,
    int2* __restrict__ brec, int E) {
  int e = blockIdx.x * blockDim.x + threadIdx.x;
  const int stride = gridDim.x * blockDim.x;
  for (; e < E; e += stride) {
    const unsigned r = (unsigned)rows[e];
    const unsigned c = (unsigned)cols[e];
    const float    v = vals[e];
    const int pos = atomicAdd(&bcursor[(r >> BSHIFT) * CUR_STRIDE], 1);
    brec[pos] = make_int2((int)((r << 16) | c), __float_as_int(v));
  }
}

// ---------------------------------------------------------------------------
// Stage 4 (fused): per-bucket in-LDS CSR finish + SpMM + bias/ReLU.
// One block per bucket: load the bucket's contiguous record range, place each
// record at its exact CSR-local LDS slot via LDS atomics, then wave w computes
// rows [w*8, w*8+8) — lane owns a float2 of the 128 features.
// ---------------------------------------------------------------------------
__global__ __launch_bounds__(256) void spmm_bucket_kernel(
    const int* __restrict__ row_start, const int2* __restrict__ brec,
    const float* __restrict__ X, const float* __restrict__ bias,
    float* __restrict__ out, int M) {
  __shared__ int2 buf[BCAP];
  __shared__ int lstart[BROWS + 1];
  __shared__ int lcur[BROWS];

  const int t  = threadIdx.x;
  const int r0 = blockIdx.x * BROWS;
  const int base = row_start[r0];

  if (t <= BROWS) {
    int idx = r0 + t; if (idx > M) idx = M;
    lstart[t] = row_start[idx] - base;
  }
  __syncthreads();
  const int nE = lstart[BROWS];
  if (t < BROWS) lcur[t] = lstart[t];
  __syncthreads();

  // place records at CSR-local positions
  for (int i = t; i < nE; i += 256) {
    const int2 rec = brec[base + i];
    const int j = (int)(((unsigned)rec.x) >> 16) - r0;   // local row
    const int p = atomicAdd(&lcur[j], 1);
    if (p < BCAP) buf[p] = rec;
  }
  __syncthreads();

  // SpMM from LDS
  const int lane = t & 63;
  const int wid  = t >> 6;
  const float2 bb = ((const float2*)bias)[lane];

  for (int j = wid * 8; j < wid * 8 + 8; ++j) {
    const int row = r0 + j;
    if (row >= M) break;
    const int s  = lstart[j];
    const int en = lstart[j + 1];

    float ax = 0.f, ay = 0.f;
    int e = s;
    for (; e + 3 < en; e += 4) {
      const int2 q0 = buf[e],     q1 = buf[e + 1];
      const int2 q2 = buf[e + 2], q3 = buf[e + 3];
      const float v0 = __int_as_float(q0.y), v1 = __int_as_float(q1.y);
      const float v2 = __int_as_float(q2.y), v3 = __int_as_float(q3.y);
      const float2 x0 = ((const float2*)(X + ((size_t)(q0.x & 0xFFFF) << 7)))[lane];
      const float2 x1 = ((const float2*)(X + ((size_t)(q1.x & 0xFFFF) << 7)))[lane];
      const float2 x2 = ((const float2*)(X + ((size_t)(q2.x & 0xFFFF) << 7)))[lane];
      const float2 x3 = ((const float2*)(X + ((size_t)(q3.x & 0xFFFF) << 7)))[lane];
      ax += v0 * x0.x + v1 * x1.x + v2 * x2.x + v3 * x3.x;
      ay += v0 * x0.y + v1 * x1.y + v2 * x2.y + v3 * x3.y;
    }
    for (; e < en; ++e) {
      const int2 q = buf[e];
      const float v = __int_as_float(q.y);
      const float2 x = ((const float2*)(X + ((size_t)(q.x & 0xFFFF) << 7)))[lane];
      ax += v * x.x;
      ay += v * x.y;
    }

    float2 res;
    res.x = fmaxf(ax + bb.x, 0.f);
    res.y = fmaxf(ay + bb.y, 0.f);
    ((float2*)(out + ((size_t)row << 7)))[lane] = res;
  }
}

extern "C" void kernel_launch(void* const* d_in, const int* in_sizes, int n_in,
                              void* d_out, int out_size, void* d_ws, size_t ws_size,
                              hipStream_t stream) {
  const float* features  = (const float*)d_in[0];
  const float* drop_mask = (const float*)d_in[1];
  const float* W         = (const float*)d_in[2];
  const float* b         = (const float*)d_in[3];
  const int*   adj_rows  = (const int*)d_in[4];
  const int*   adj_cols  = (const int*)d_in[5];
  const float* adj_vals  = (const float*)d_in[6];

  float* out = (float*)d_out;

  const int M = in_sizes[0] / F_IN;            // 50000
  const int E = in_sizes[4];                   // 1.6M
  const int nchunk = (M + 255) / 256;          // 196
  const int nb = (M + BROWS - 1) / BROWS;      // 1563 buckets

  // Workspace layout (~38.9 MB)
  float* X        = (float*)d_ws;              // M*128 floats
  int2*  brec     = (int2*)(X + (size_t)M * F_OUT);      // E records (8B)
  int*   count    = (int*)(brec + E);          // M
  int*   row_start= count + M;                 // M+1
  int*   partial  = row_start + M + 1;         // nchunk
  int*   bcursor  = partial + nchunk;          // nb * CUR_STRIDE

  hipMemsetAsync(count, 0, (size_t)M * sizeof(int), stream);

  gemm_dropout_kernel<<<(M + BM - 1) / BM, 256, 0, stream>>>(features, drop_mask, W, X, M);

  hist_kernel<<<2048, 256, 0, stream>>>(adj_rows, count, E);
  chunk_reduce_kernel<<<nchunk, 256, 0, stream>>>(count, partial, M);
  scan_partials_kernel<<<1, 256, 0, stream>>>(partial, nchunk, row_start, M);
  chunk_scan_kernel<<<nchunk, 256, 0, stream>>>(count, partial, row_start, bcursor, M);
  bucket_scatter_kernel<<<2048, 256, 0, stream>>>(adj_rows, adj_cols, adj_vals,
                                                  bcursor, brec, E);
  spmm_bucket_kernel<<<nb, 256, 0, stream>>>(row_start, brec, X, b, out, M);
}

// Round 4
// 482.258 us; speedup vs baseline: 6.1635x; 1.1948x over previous
//
#include <hip/hip_runtime.h>

// Problem constants: N=50000, F_IN=512, F_OUT=128, E=1.6M
#define F_IN   512
#define F_OUT  128
#define BMG    64        // gemm tile rows
#define BK     32

#define BROWS  32        // rows per bucket
#define BSHIFT 5
#define NBMAX  2048      // max buckets representable in LDS tables (M <= 65536)
#define SCAP   2048      // per-bucket record capacity in spmm LDS staging
#define NBLK   256       // blocks in the binning/scatter passes (must match S1/S3)

// ---------------------------------------------------------------------------
// GEMM: X[M,128] = (A * Mask) @ B.  64x128 tile, 256 threads, 4x8 micro-tile.
// 782 blocks -> ~3 blocks/CU; ~26KB LDS, target 16+ waves/CU.
// ---------------------------------------------------------------------------
__global__ __launch_bounds__(256, 4) void gemm_dropout_kernel(
    const float* __restrict__ A, const float* __restrict__ Mask,
    const float* __restrict__ B, float* __restrict__ X, int M) {
  __shared__ float As[BK][BMG + 4];
  __shared__ float Bs[BK][F_OUT + 4];

  const int tid = threadIdx.x;
  const int tx = tid & 15;         // 16 col groups
  const int ty = tid >> 4;         // 16 row groups
  const int bm = blockIdx.x * BMG;

  float acc[4][8];
#pragma unroll
  for (int i = 0; i < 4; ++i)
#pragma unroll
    for (int j = 0; j < 8; ++j) acc[i][j] = 0.f;

  for (int k0 = 0; k0 < F_IN; k0 += BK) {
    // A-tile: 64 rows x 32 k = 512 float4 slots, 2 per thread (fused dropout)
#pragma unroll
    for (int i = 0; i < 2; ++i) {
      int idx = tid + i * 256;
      int r = idx >> 3;
      int c = (idx & 7) << 2;
      int row = bm + r; if (row >= M) row = M - 1;
      const float4 a = *(const float4*)(A    + (size_t)row * F_IN + k0 + c);
      const float4 m = *(const float4*)(Mask + (size_t)row * F_IN + k0 + c);
      As[c + 0][r] = a.x * m.x;
      As[c + 1][r] = a.y * m.y;
      As[c + 2][r] = a.z * m.z;
      As[c + 3][r] = a.w * m.w;
    }
    // B-tile: 32 k x 128 n = 1024 float4 slots, 4 per thread
#pragma unroll
    for (int i = 0; i < 4; ++i) {
      int idx = tid + i * 256;
      int r = idx >> 5;
      int c = (idx & 31) << 2;
      *(float4*)(&Bs[r][c]) = *(const float4*)(B + (size_t)(k0 + r) * F_OUT + c);
    }
    __syncthreads();

#pragma unroll
    for (int kk = 0; kk < BK; ++kk) {
      float a[4], bb[8];
      *(float4*)(a)      = *(const float4*)(&As[kk][ty * 4]);
      *(float4*)(bb)     = *(const float4*)(&Bs[kk][tx * 4]);
      *(float4*)(bb + 4) = *(const float4*)(&Bs[kk][tx * 4 + 64]);
#pragma unroll
      for (int i = 0; i < 4; ++i)
#pragma unroll
        for (int j = 0; j < 8; ++j) acc[i][j] += a[i] * bb[j];
    }
    __syncthreads();
  }

#pragma unroll
  for (int i = 0; i < 4; ++i) {
    const int row = bm + ty * 4 + i;
    if (row < M) {
      float4 lo = make_float4(acc[i][0], acc[i][1], acc[i][2], acc[i][3]);
      float4 hi = make_float4(acc[i][4], acc[i][5], acc[i][6], acc[i][7]);
      *(float4*)(X + (size_t)row * F_OUT + tx * 4)      = lo;
      *(float4*)(X + (size_t)row * F_OUT + 64 + tx * 4) = hi;
    }
  }
}

// ---------------------------------------------------------------------------
// S1: per-block LDS histogram over buckets; write private hist row (NO atomics
// to global). Chunk assignment must match S3 exactly.
// ---------------------------------------------------------------------------
__global__ __launch_bounds__(256) void block_hist_kernel(
    const int* __restrict__ rows, int* __restrict__ hist_all, int E, int NB) {
  __shared__ int h[NBMAX];
  const int t = threadIdx.x;
  const int blk = blockIdx.x;
  for (int i = t; i < NB; i += 256) h[i] = 0;
  __syncthreads();

  const int chunk = (E + NBLK - 1) / NBLK;
  const int s = blk * chunk;
  const int e = min(E, s + chunk);
  for (int i = s + t; i < e; i += 256)
    atomicAdd(&h[((unsigned)rows[i]) >> BSHIFT], 1);     // LDS atomic
  __syncthreads();

  for (int i = t; i < NB; i += 256) hist_all[(size_t)blk * NB + i] = h[i];
}

// ---------------------------------------------------------------------------
// S2a: per-bucket exclusive scan down the block axis (in place), totals out.
// Thread b walks hist_all[*][b]; consecutive b -> coalesced.
// ---------------------------------------------------------------------------
__global__ __launch_bounds__(256) void col_scan_kernel(
    int* __restrict__ hist_all, int* __restrict__ totals, int NB) {
  const int b = blockIdx.x * 256 + threadIdx.x;
  if (b >= NB) return;
  int run = 0;
  for (int blk = 0; blk < NBLK; ++blk) {
    const size_t idx = (size_t)blk * NB + b;
    const int v = hist_all[idx];
    hist_all[idx] = run;
    run += v;
  }
  totals[b] = run;
}

// ---------------------------------------------------------------------------
// S2b: exclusive scan of bucket totals -> bucket_start[0..NB] (one block).
// Each thread owns 8 consecutive entries (covers NB <= 2048).
// ---------------------------------------------------------------------------
__global__ __launch_bounds__(256) void scan_totals_kernel(
    const int* __restrict__ totals, int* __restrict__ bucket_start, int NB) {
  __shared__ int s[256];
  const int t = threadIdx.x;
  int loc[8];
  int sum = 0;
#pragma unroll
  for (int k = 0; k < 8; ++k) {
    const int idx = t * 8 + k;
    const int v = (idx < NB) ? totals[idx] : 0;
    loc[k] = sum;            // exclusive prefix within thread
    sum += v;
  }
  s[t] = sum;
  __syncthreads();
#pragma unroll
  for (int off = 1; off < 256; off <<= 1) {
    int y = (t >= off) ? s[t - off] : 0;
    __syncthreads();
    s[t] += y;
    __syncthreads();
  }
  const int base = s[t] - sum;   // exclusive across threads
#pragma unroll
  for (int k = 0; k < 8; ++k) {
    const int idx = t * 8 + k;
    if (idx < NB) bucket_start[idx] = base + loc[k];
  }
  if (t == 255) bucket_start[NB] = s[255];   // == E
}

// ---------------------------------------------------------------------------
// S3: place packed records into reserved contiguous runs via LDS cursors.
// record = ((row<<16)|col, bits(val)).  Zero global atomics.
// ---------------------------------------------------------------------------
__global__ __launch_bounds__(256) void scatter_place_kernel(
    const int* __restrict__ rows, const int* __restrict__ cols,
    const float* __restrict__ vals, const int* __restrict__ hist_all,
    const int* __restrict__ bucket_start, int2* __restrict__ brec,
    int E, int NB) {
  __shared__ int cur[NBMAX];
  const int t = threadIdx.x;
  const int blk = blockIdx.x;
  for (int i = t; i < NB; i += 256)
    cur[i] = bucket_start[i] + hist_all[(size_t)blk * NB + i];
  __syncthreads();

  const int chunk = (E + NBLK - 1) / NBLK;
  const int s = blk * chunk;
  const int e = min(E, s + chunk);
  for (int i = s + t; i < e; i += 256) {
    const unsigned r = (unsigned)rows[i];
    const unsigned c = (unsigned)cols[i];
    const float    v = vals[i];
    const int pos = atomicAdd(&cur[r >> BSHIFT], 1);    // LDS atomic
    brec[pos] = make_int2((int)((r << 16) | c), __float_as_int(v));
  }
}

// ---------------------------------------------------------------------------
// SpMM (fused): one block per bucket (32 rows). Stage records, build local
// CSR in LDS (32 counters + tiny scan), row-sort in LDS, then gather X rows
// (lane owns float2 of 128 features) + fused bias/ReLU, one write per output.
// ---------------------------------------------------------------------------
__global__ __launch_bounds__(256) void spmm_bucket_kernel(
    const int* __restrict__ bucket_start, const int2* __restrict__ brec,
    const float* __restrict__ X, const float* __restrict__ bias,
    float* __restrict__ out, int M) {
  __shared__ int2 arrival[SCAP];
  __shared__ int2 sorted[SCAP];
  __shared__ int lstart[BROWS + 1];
  __shared__ int lcnt[BROWS];
  __shared__ int lcur[BROWS];

  const int t  = threadIdx.x;
  const int r0 = blockIdx.x * BROWS;
  const int base = bucket_start[blockIdx.x];
  int nE = bucket_start[blockIdx.x + 1] - base;
  if (nE > SCAP) nE = SCAP;   // safety clamp (avg ~1024, max ~1.2K for this data)

  if (t < BROWS) lcnt[t] = 0;
  __syncthreads();

  for (int i = t; i < nE; i += 256) {
    const int2 rec = brec[base + i];
    arrival[i] = rec;
    atomicAdd(&lcnt[(((unsigned)rec.x) >> 16) - r0], 1);   // LDS atomic
  }
  __syncthreads();

  if (t == 0) {
    int run = 0;
#pragma unroll
    for (int j = 0; j < BROWS; ++j) {
      lstart[j] = run;
      lcur[j] = run;
      run += lcnt[j];
    }
    lstart[BROWS] = run;
  }
  __syncthreads();

  for (int i = t; i < nE; i += 256) {
    const int2 rec = arrival[i];
    const int j = (int)(((unsigned)rec.x) >> 16) - r0;
    const int p = atomicAdd(&lcur[j], 1);                  // LDS atomic
    sorted[p] = rec;
  }
  __syncthreads();

  const int lane = t & 63;
  const int wid  = t >> 6;
  const float2 bb = ((const float2*)bias)[lane];

  for (int j = wid * 8; j < wid * 8 + 8; ++j) {
    const int row = r0 + j;
    if (row >= M) break;
    const int s  = lstart[j];
    const int en = lstart[j + 1];

    float ax = 0.f, ay = 0.f;
    int e = s;
    for (; e + 3 < en; e += 4) {
      const int2 q0 = sorted[e],     q1 = sorted[e + 1];
      const int2 q2 = sorted[e + 2], q3 = sorted[e + 3];
      const float v0 = __int_as_float(q0.y), v1 = __int_as_float(q1.y);
      const float v2 = __int_as_float(q2.y), v3 = __int_as_float(q3.y);
      const float2 x0 = ((const float2*)(X + ((size_t)(q0.x & 0xFFFF) << 7)))[lane];
      const float2 x1 = ((const float2*)(X + ((size_t)(q1.x & 0xFFFF) << 7)))[lane];
      const float2 x2 = ((const float2*)(X + ((size_t)(q2.x & 0xFFFF) << 7)))[lane];
      const float2 x3 = ((const float2*)(X + ((size_t)(q3.x & 0xFFFF) << 7)))[lane];
      ax += v0 * x0.x + v1 * x1.x + v2 * x2.x + v3 * x3.x;
      ay += v0 * x0.y + v1 * x1.y + v2 * x2.y + v3 * x3.y;
    }
    for (; e < en; ++e) {
      const int2 q = sorted[e];
      const float v = __int_as_float(q.y);
      const float2 x = ((const float2*)(X + ((size_t)(q.x & 0xFFFF) << 7)))[lane];
      ax += v * x.x;
      ay += v * x.y;
    }

    float2 res;
    res.x = fmaxf(ax + bb.x, 0.f);
    res.y = fmaxf(ay + bb.y, 0.f);
    ((float2*)(out + ((size_t)row << 7)))[lane] = res;
  }
}

extern "C" void kernel_launch(void* const* d_in, const int* in_sizes, int n_in,
                              void* d_out, int out_size, void* d_ws, size_t ws_size,
                              hipStream_t stream) {
  const float* features  = (const float*)d_in[0];
  const float* drop_mask = (const float*)d_in[1];
  const float* W         = (const float*)d_in[2];
  const float* b         = (const float*)d_in[3];
  const int*   adj_rows  = (const int*)d_in[4];
  const int*   adj_cols  = (const int*)d_in[5];
  const float* adj_vals  = (const float*)d_in[6];

  float* out = (float*)d_out;

  const int M  = in_sizes[0] / F_IN;           // 50000
  const int E  = in_sizes[4];                  // 1.6M
  const int NB = (M + BROWS - 1) / BROWS;      // 1563 buckets

  // Workspace layout (~41 MB): X | brec | hist_all | totals | bucket_start
  float* X            = (float*)d_ws;                       // M*128 floats
  int2*  brec         = (int2*)(X + (size_t)M * F_OUT);     // E records (8B)
  int*   hist_all     = (int*)(brec + E);                   // NBLK * NB
  int*   totals       = hist_all + (size_t)NBLK * NB;       // NB
  int*   bucket_start = totals + NB;                        // NB + 1

  gemm_dropout_kernel<<<(M + BMG - 1) / BMG, 256, 0, stream>>>(
      features, drop_mask, W, X, M);

  block_hist_kernel<<<NBLK, 256, 0, stream>>>(adj_rows, hist_all, E, NB);
  col_scan_kernel<<<(NB + 255) / 256, 256, 0, stream>>>(hist_all, totals, NB);
  scan_totals_kernel<<<1, 256, 0, stream>>>(totals, bucket_start, NB);
  scatter_place_kernel<<<NBLK, 256, 0, stream>>>(adj_rows, adj_cols, adj_vals,
                                                 hist_all, bucket_start, brec, E, NB);
  spmm_bucket_kernel<<<NB, 256, 0, stream>>>(bucket_start, brec, X, b, out, M);
}